// Round 2
// baseline (1355.481 us; speedup 1.0000x reference)
//
#include <hip/hip_runtime.h>
#include <hip/hip_bf16.h>
#include <cstdint>

#define B 128
#define T 400
#define H 512
#define H2 1024
#define H4 2048
#define E 128
#define V 50000
#define KXC 1152   // 2H+E
#define KPG 2176   // 4H+E
#define KO1 1536   // 3H
#define EPSF 1e-12f

// output element offsets (element counts identical for bf16/f32)
#define OFF_FIN 0
#define OFF_H   (B*V)
#define OFF_C   (OFF_H + B*H)
#define OFF_CT  (OFF_C + B*H)
#define OFF_AT  (OFF_CT + B*H2)
#define OFF_PG  (OFF_AT + B*T)
#define OFF_COV (OFF_PG + B)

// ---------------- IO policies: bf16 vs f32 ----------------
struct IOb {
  using OT = __hip_bfloat16;
  static __device__ __forceinline__ bool want(const float* fl){ return fl[0] > 0.5f; }
  static __device__ __forceinline__ float ld(const void* p, size_t i){
    return __uint_as_float(((unsigned)((const unsigned short*)p)[i]) << 16);
  }
  static __device__ __forceinline__ void ld8(const void* p, size_t i, float* f){
    uint4 u = *reinterpret_cast<const uint4*>((const unsigned short*)p + i);
    f[0]=__uint_as_float(u.x<<16); f[1]=__uint_as_float(u.x&0xffff0000u);
    f[2]=__uint_as_float(u.y<<16); f[3]=__uint_as_float(u.y&0xffff0000u);
    f[4]=__uint_as_float(u.z<<16); f[5]=__uint_as_float(u.z&0xffff0000u);
    f[6]=__uint_as_float(u.w<<16); f[7]=__uint_as_float(u.w&0xffff0000u);
  }
  static __device__ __forceinline__ void ld4(const void* p, size_t i, float* f){
    uint2 u = *reinterpret_cast<const uint2*>((const unsigned short*)p + i);
    f[0]=__uint_as_float(u.x<<16); f[1]=__uint_as_float(u.x&0xffff0000u);
    f[2]=__uint_as_float(u.y<<16); f[3]=__uint_as_float(u.y&0xffff0000u);
  }
  static __device__ __forceinline__ void st(void* p, size_t i, float v){
    ((__hip_bfloat16*)p)[i] = __float2bfloat16(v);
  }
  static __device__ __forceinline__ void st8(void* p, size_t i, const float* f){
    __hip_bfloat16 h[8];
    #pragma unroll
    for(int j=0;j<8;j++) h[j]=__float2bfloat16(f[j]);
    *reinterpret_cast<uint4*>((__hip_bfloat16*)p + i) = *reinterpret_cast<const uint4*>(h);
  }
};
struct IOf {
  using OT = float;
  static __device__ __forceinline__ bool want(const float* fl){ return fl[0] < 0.5f; }
  static __device__ __forceinline__ float ld(const void* p, size_t i){
    return ((const float*)p)[i];
  }
  static __device__ __forceinline__ void ld8(const void* p, size_t i, float* f){
    const float* q = (const float*)p + i;
    float4 a = *reinterpret_cast<const float4*>(q);
    float4 b = *reinterpret_cast<const float4*>(q+4);
    f[0]=a.x; f[1]=a.y; f[2]=a.z; f[3]=a.w;
    f[4]=b.x; f[5]=b.y; f[6]=b.z; f[7]=b.w;
  }
  static __device__ __forceinline__ void ld4(const void* p, size_t i, float* f){
    float4 a = *reinterpret_cast<const float4*>((const float*)p + i);
    f[0]=a.x; f[1]=a.y; f[2]=a.z; f[3]=a.w;
  }
  static __device__ __forceinline__ void st(void* p, size_t i, float v){
    ((float*)p)[i] = v;
  }
  static __device__ __forceinline__ void st8(void* p, size_t i, const float* f){
    float* q = (float*)p + i;
    *reinterpret_cast<float4*>(q)   = make_float4(f[0],f[1],f[2],f[3]);
    *reinterpret_cast<float4*>(q+4) = make_float4(f[4],f[5],f[6],f[7]);
  }
};

__device__ __forceinline__ float ftanh(float x){
  x = fminf(10.f, fmaxf(-10.f, x));
  float a = __expf(2.f*x);
  return 1.f - 2.f/(a+1.f);
}
__device__ __forceinline__ float fsig(float x){ return 1.f/(1.f+__expf(-x)); }

__device__ __forceinline__ float waveSum(float v){
  #pragma unroll
  for(int o=32;o>0;o>>=1) v += __shfl_down(v,o);
  return v;
}
__device__ __forceinline__ float waveMax(float v){
  #pragma unroll
  for(int o=32;o>0;o>>=1) v = fmaxf(v,__shfl_down(v,o));
  return v;
}

// detect input dtype from mask_select (all ones): bf16 pair 1.0,1.0 = 0x3F803F80
__global__ void k_detect(const void* mask, float* flagp){
  if(blockIdx.x==0 && threadIdx.x==0){
    unsigned u = *(const unsigned*)mask;
    flagp[0] = (((u>>16)==0x3F80u) && ((u&0xFFFFu)==0x3F80u)) ? 1.f : 0.f;
  }
}

__global__ void k_zero(float* p, int n){
  int i = blockIdx.x*256+threadIdx.x; if(i<n) p[i]=0.f;
}

// K1: y_emb gather + x = [c_t_1, y_emb] @ W_xc^T + b_xc   (grid B, block 128)
template<class IO>
__global__ void k_embed_x(const float* flag, const int* y, const void* c_t_1, const void* emb,
                          const void* W_xc, const void* b_xc, float* ws_x){
  if(!IO::want(flag)) return;
  __shared__ float cat[KXC];
  int b = blockIdx.x, tid = threadIdx.x;
  int yb = y[b];
  IO::ld8(c_t_1, (size_t)b*H2 + tid*8, &cat[tid*8]);
  if(tid < 16) IO::ld8(emb, (size_t)yb*E + tid*8, &cat[H2 + tid*8]);
  __syncthreads();
  float acc = IO::ld(b_xc, tid);
  for(int k=0;k<KXC;k+=8){
    float f[8]; IO::ld8(W_xc, (size_t)tid*KXC + k, f);
    #pragma unroll
    for(int i=0;i<8;i++) acc += f[i]*cat[k+i];
  }
  ws_x[b*E+tid] = acc;
}

// K2: gates + LSTM cell  (grid B, block 256)
template<class IO>
__global__ void k_lstm(const float* flag, const float* ws_x, const void* h0, const void* c0,
                       const void* W_ih, const void* W_hh, const void* b_ih, const void* b_hh,
                       float* ws_h, float* ws_c, void* dout){
  if(!IO::want(flag)) return;
  __shared__ float xs[E], hs[H], gates[H4];
  int b=blockIdx.x, tid=threadIdx.x;
  if(tid < E) xs[tid] = ws_x[b*E+tid];
  for(int k=tid;k<H;k+=256) hs[k] = IO::ld(h0, (size_t)b*H+k);
  __syncthreads();
  #pragma unroll
  for(int s=0;s<8;s++){
    int j = tid + 256*s;
    float acc = IO::ld(b_ih, j) + IO::ld(b_hh, j);
    for(int k=0;k<E;k+=8){ float f[8]; IO::ld8(W_ih, (size_t)j*E + k, f);
      #pragma unroll
      for(int i=0;i<8;i++) acc += f[i]*xs[k+i]; }
    for(int k=0;k<H;k+=8){ float f[8]; IO::ld8(W_hh, (size_t)j*H + k, f);
      #pragma unroll
      for(int i=0;i<8;i++) acc += f[i]*hs[k+i]; }
    gates[j] = acc;
  }
  __syncthreads();
  #pragma unroll
  for(int s=0;s<2;s++){
    int n = tid + 256*s;
    float ig = fsig(gates[n]);
    float fg = fsig(gates[H+n]);
    float gg = ftanh(gates[2*H+n]);
    float og = fsig(gates[3*H+n]);
    float c = fg*IO::ld(c0, (size_t)b*H+n) + ig*gg;
    float h = og*ftanh(c);
    ws_c[b*H+n]=c; ws_h[b*H+n]=h;
    IO::st(dout, (size_t)OFF_C + b*H+n, c);
    IO::st(dout, (size_t)OFF_H + b*H+n, h);
  }
}

// K3: dec_fea = s_t_hat @ W_dp^T + b_dp  (grid B, block 256)
template<class IO>
__global__ void k_decfea(const float* flag, const float* ws_h, const float* ws_c,
                         const void* W_dp, const void* b_dp, float* ws_dec){
  if(!IO::want(flag)) return;
  __shared__ float s[H2];
  int b=blockIdx.x, tid=threadIdx.x;
  for(int k=tid;k<H;k+=256){ s[k]=ws_h[b*H+k]; s[H+k]=ws_c[b*H+k]; }
  __syncthreads();
  #pragma unroll
  for(int q=0;q<4;q++){
    int j = tid + 256*q;
    float acc = IO::ld(b_dp, j);
    for(int k=0;k<H2;k+=8){ float f[8]; IO::ld8(W_dp, (size_t)j*H2 + k, f);
      #pragma unroll
      for(int i=0;i<8;i++) acc += f[i]*s[k+i]; }
    ws_dec[b*H2+j]=acc;
  }
}

// K4: attention scores  (grid B*25, block 256 = 4 waves, 16 t per block)
template<class IO>
__global__ void k_scores(const float* flag, const void* enc_feat, const float* ws_dec,
                         const void* W_c, const void* v_w, const void* coverage,
                         float* ws_scores){
  if(!IO::want(flag)) return;
  int blk = blockIdx.x;
  int b  = blk / (T/16);
  int tb = (blk % (T/16))*16;
  int tid = threadIdx.x;
  int wave = tid >> 6, lane = tid & 63;
  int n0 = lane*16;
  float dec[16], wc[16], vw[16];
  #pragma unroll
  for(int i=0;i<16;i+=4){
    float4 v4 = *reinterpret_cast<const float4*>(ws_dec + b*H2 + n0 + i);
    dec[i]=v4.x; dec[i+1]=v4.y; dec[i+2]=v4.z; dec[i+3]=v4.w;
  }
  IO::ld8(W_c, n0, wc); IO::ld8(W_c, n0+8, wc+8);
  IO::ld8(v_w, n0, vw); IO::ld8(v_w, n0+8, vw+8);
  #pragma unroll
  for(int it=0; it<4; ++it){
    int t = tb + wave*4 + it;
    float cov = IO::ld(coverage, (size_t)b*T + t);
    size_t base = ((size_t)b*T + t)*H2 + n0;
    float ef[16]; IO::ld8(enc_feat, base, ef); IO::ld8(enc_feat, base+8, ef+8);
    float sum=0.f;
    #pragma unroll
    for(int i=0;i<16;i++){
      float s = ef[i] + dec[i] + cov*wc[i];
      sum += ftanh(s)*vw[i];
    }
    sum = waveSum(sum);
    if(lane==0) ws_scores[b*T + t] = sum;
  }
}

// K5: softmax over T + mask + renorm + coverage_next  (grid B, block 512)
template<class IO>
__global__ void k_attn(const float* flag, const float* ws_scores, const void* mask,
                       const void* coverage, float* ws_attn, void* dout){
  if(!IO::want(flag)) return;
  __shared__ float red[8];
  __shared__ float bc0, bc1, bc2;
  int b=blockIdx.x, tid=threadIdx.x;
  int lane = tid & 63, w = tid >> 6;
  float s = (tid<T)? ws_scores[b*T+tid] : -3.0e38f;
  float m = waveMax(s);
  if(lane==0) red[w]=m;
  __syncthreads();
  if(tid==0){ float v=red[0]; for(int i=1;i<8;i++)v=fmaxf(v,red[i]); bc0=v; }
  __syncthreads();
  float e = (tid<T)? __expf(s-bc0) : 0.f;
  float sm = waveSum(e);
  if(lane==0) red[w]=sm;
  __syncthreads();
  if(tid==0){ float v=0; for(int i=0;i<8;i++)v+=red[i]; bc1=v; }
  __syncthreads();
  float attn_ = (tid<T)? (e/bc1)*IO::ld(mask, (size_t)b*T+tid) : 0.f;
  float s2 = waveSum(attn_);
  if(lane==0) red[w]=s2;
  __syncthreads();
  if(tid==0){ float v=0; for(int i=0;i<8;i++)v+=red[i]; bc2=v; }
  __syncthreads();
  float attn = attn_/(bc2+EPSF);
  if(tid<T){
    ws_attn[b*T+tid]=attn;
    IO::st(dout, (size_t)OFF_AT + b*T+tid, attn);
    IO::st(dout, (size_t)OFF_COV + b*T+tid, IO::ld(coverage,(size_t)b*T+tid)+attn);
  }
}

// K6: c_t = attn @ encoder_outputs, split 8-way over t  (grid B*8, block 256)
template<class IO>
__global__ void k_ctx(const float* flag, const void* enc_out, const float* ws_attn, float* ws_ct){
  if(!IO::want(flag)) return;
  __shared__ float at[50];
  int b = blockIdx.x>>3, ch = blockIdx.x&7, tid=threadIdx.x;
  if(tid<50) at[tid] = ws_attn[b*T + ch*50 + tid];
  __syncthreads();
  int n0 = tid*4;
  float a0=0,a1=0,a2=0,a3=0;
  size_t base = ((size_t)b*T + ch*50)*H2 + n0;
  for(int t=0;t<50;t++){
    float a = at[t];
    float f[4]; IO::ld4(enc_out, base, f);
    a0 += a*f[0]; a1 += a*f[1]; a2 += a*f[2]; a3 += a*f[3];
    base += H2;
  }
  atomicAdd(&ws_ct[b*H2+n0+0], a0);
  atomicAdd(&ws_ct[b*H2+n0+1], a1);
  atomicAdd(&ws_ct[b*H2+n0+2], a2);
  atomicAdd(&ws_ct[b*H2+n0+3], a3);
}

// K7: p_gen + write c_t out  (grid B, block 256)
template<class IO>
__global__ void k_pgen(const float* flag, const float* ws_ct, const float* ws_h,
                       const float* ws_c, const float* ws_x,
                       const void* W_pg, const void* b_pg, float* ws_pg, void* dout){
  if(!IO::want(flag)) return;
  __shared__ float red[4];
  int b=blockIdx.x, tid=threadIdx.x;
  int lane = tid&63, w = tid>>6;
  float part=0.f;
  for(int k=tid;k<KPG;k+=256){
    float xv;
    if(k<H2)            xv = ws_ct[b*H2+k];
    else if(k<H2+H)     xv = ws_h[b*H+(k-H2)];
    else if(k<2*H2)     xv = ws_c[b*H+(k-H2-H)];
    else                xv = ws_x[b*E + (k-2*H2)];
    part += xv * IO::ld(W_pg, k);
  }
  part = waveSum(part);
  if(lane==0) red[w]=part;
  __syncthreads();
  if(tid==0){
    float v = red[0]+red[1]+red[2]+red[3] + IO::ld(b_pg, 0);
    float pg = fsig(v);
    ws_pg[b]=pg;
    IO::st(dout, (size_t)OFF_PG + b, pg);
  }
  for(int k=tid;k<H2;k+=256) IO::st(dout, (size_t)OFF_CT + b*H2+k, ws_ct[b*H2+k]);
}

// K8: o1 = [h, c_t] @ W_o1^T + b_o1  (grid B, block 256)
template<class IO>
__global__ void k_o1(const float* flag, const float* ws_h, const float* ws_ct,
                     const void* W_o1, const void* b_o1, float* ws_o1){
  if(!IO::want(flag)) return;
  __shared__ float s[KO1];
  int b=blockIdx.x, tid=threadIdx.x;
  for(int k=tid;k<H;k+=256)  s[k]   = ws_h[b*H+k];
  for(int k=tid;k<H2;k+=256) s[H+k] = ws_ct[b*H2+k];
  __syncthreads();
  #pragma unroll
  for(int q=0;q<2;q++){
    int j = tid+256*q;
    float acc = IO::ld(b_o1, j);
    for(int k=0;k<KO1;k+=8){ float f[8]; IO::ld8(W_o1, (size_t)j*KO1 + k, f);
      #pragma unroll
      for(int i=0;i<8;i++) acc += f[i]*s[k+i]; }
    ws_o1[b*H+j]=acc;
  }
}

// K9: logits = o1 @ W_o2^T + b_o2   (grid ceil(V/64), block 256; tile 128b x 64v, K-chunk 32)
template<class IO>
__global__ __launch_bounds__(256) void k_logits(const float* flag, const float* ws_o1,
                                                const void* W_o2, const void* b_o2,
                                                float* ws_logits){
  if(!IO::want(flag)) return;
  __shared__ float o1s[32][132];
  __shared__ float wvs[32][68];
  int v0 = blockIdx.x * 64;
  int tid = threadIdx.x;
  int bg = tid & 31;   // b = bg*4 + i
  int vg = tid >> 5;   // v = v0 + vg*8 + j
  float acc[4][8];
  #pragma unroll
  for(int i=0;i<4;i++){
    #pragma unroll
    for(int j=0;j<8;j++) acc[i][j]=0.f; }
  for(int k0=0;k0<H;k0+=32){
    __syncthreads();
    { // stage o1: 128 rows x 32 k, 16 floats per thread
      int bb = tid>>1, kc = (tid&1)*16;
      const float* q = ws_o1 + bb*H + k0 + kc;
      float4 q0 = *reinterpret_cast<const float4*>(q);
      float4 q1 = *reinterpret_cast<const float4*>(q+4);
      float4 q2 = *reinterpret_cast<const float4*>(q+8);
      float4 q3 = *reinterpret_cast<const float4*>(q+12);
      o1s[kc+ 0][bb]=q0.x; o1s[kc+ 1][bb]=q0.y; o1s[kc+ 2][bb]=q0.z; o1s[kc+ 3][bb]=q0.w;
      o1s[kc+ 4][bb]=q1.x; o1s[kc+ 5][bb]=q1.y; o1s[kc+ 6][bb]=q1.z; o1s[kc+ 7][bb]=q1.w;
      o1s[kc+ 8][bb]=q2.x; o1s[kc+ 9][bb]=q2.y; o1s[kc+10][bb]=q2.z; o1s[kc+11][bb]=q2.w;
      o1s[kc+12][bb]=q3.x; o1s[kc+13][bb]=q3.y; o1s[kc+14][bb]=q3.z; o1s[kc+15][bb]=q3.w;
    }
    { // stage W_o2: 64 v x 32 k, 8 per thread
      int vv = tid>>2, c = (tid&3)*8;
      int v = v0+vv; bool ok = (v<V);
      float f[8]; IO::ld8(W_o2, (size_t)(ok? v : (V-1))*H + k0 + c, f);
      #pragma unroll
      for(int j=0;j<8;j++) wvs[c+j][vv] = ok? f[j] : 0.f;
    }
    __syncthreads();
    #pragma unroll 8
    for(int kk=0;kk<32;kk++){
      float4 a  = *reinterpret_cast<const float4*>(&o1s[kk][bg*4]);
      float4 w0 = *reinterpret_cast<const float4*>(&wvs[kk][vg*8]);
      float4 w1 = *reinterpret_cast<const float4*>(&wvs[kk][vg*8+4]);
      float av[4]={a.x,a.y,a.z,a.w};
      float wv[8]={w0.x,w0.y,w0.z,w0.w,w1.x,w1.y,w1.z,w1.w};
      #pragma unroll
      for(int i=0;i<4;i++){
        #pragma unroll
        for(int j=0;j<8;j++) acc[i][j] += av[i]*wv[j];
      }
    }
  }
  #pragma unroll
  for(int i=0;i<4;i++){
    int bb = bg*4+i;
    #pragma unroll
    for(int j=0;j<8;j++){
      int v = v0 + vg*8 + j;
      if(v<V) ws_logits[(size_t)bb*V + v] = acc[i][j] + IO::ld(b_o2, v);
    }
  }
}

// K10a: vocab softmax * p_gen, simple 3-pass  (grid B, block 256)
__global__ void k_vsoft(const float* lg, const float* pg, float* fin){
  __shared__ float red[4];
  __shared__ float bcast;
  int b=blockIdx.x, tid=threadIdx.x;
  int lane = tid&63, w = tid>>6;
  float m=-3.0e38f;
  for(int v=tid; v<V; v+=256) m = fmaxf(m, lg[(size_t)b*V+v]);
  m = waveMax(m);
  if(lane==0) red[w]=m;
  __syncthreads();
  if(tid==0) bcast = fmaxf(fmaxf(red[0],red[1]),fmaxf(red[2],red[3]));
  __syncthreads();
  float mx = bcast;
  float s=0.f;
  for(int v=tid; v<V; v+=256) s += __expf(lg[(size_t)b*V+v]-mx);
  s = waveSum(s);
  if(lane==0) red[w]=s;
  __syncthreads();
  if(tid==0) bcast = red[0]+red[1]+red[2]+red[3];
  __syncthreads();
  float scale = pg[b] / bcast;
  for(int v=tid; v<V; v+=256) fin[(size_t)b*V+v] = __expf(lg[(size_t)b*V+v]-mx)*scale;
}

// K10b: scatter-add (1-p_gen)*attn  (grid ceil(B*T/256))
__global__ void k_scatter(const int* ext, const float* ws_attn, const float* ws_pg, float* ws_final){
  int i = blockIdx.x*256+threadIdx.x;
  if(i>=B*T) return;
  int b=i/T;
  float add = (1.f-ws_pg[b])*ws_attn[i];
  atomicAdd(&ws_final[(size_t)b*V + ext[i]], add);
}

// K10c: store final dist to out, 8/thread
template<class IO>
__global__ void k_tostore(const float* flag, const float* src, void* dout, int n8){
  if(!IO::want(flag)) return;
  int i = blockIdx.x*256+threadIdx.x;
  if(i>=n8) return;
  size_t off = (size_t)i*8;
  float f[8];
  const float* q = src + off;
  float4 a = *reinterpret_cast<const float4*>(q);
  float4 b = *reinterpret_cast<const float4*>(q+4);
  f[0]=a.x; f[1]=a.y; f[2]=a.z; f[3]=a.w; f[4]=b.x; f[5]=b.y; f[6]=b.z; f[7]=b.w;
  IO::st8(dout, (size_t)OFF_FIN + off, f);
}

extern "C" void kernel_launch(void* const* d_in, const int* in_sizes, int n_in,
                              void* d_out, int out_size, void* d_ws, size_t ws_size,
                              hipStream_t stream){
  const int* y_t_1 = (const int*)d_in[0];
  const void* h0   =d_in[1];  const void* c0   =d_in[2];  const void* c_t_1=d_in[3];
  const void* enc_out=d_in[4]; const void* enc_feat=d_in[5]; const void* mask=d_in[6];
  const int* ext = (const int*)d_in[7];
  const void* coverage=d_in[8]; const void* emb=d_in[9];  const void* W_c=d_in[10];
  const void* W_dp=d_in[11];   const void* b_dp=d_in[12]; const void* v_w=d_in[13];
  const void* W_xc=d_in[14];   const void* b_xc=d_in[15];
  const void* W_ih=d_in[16];   const void* W_hh=d_in[17];
  const void* b_ih=d_in[18];   const void* b_hh=d_in[19];
  const void* W_pg=d_in[20];   const void* b_pg=d_in[21];
  const void* W_o1=d_in[22];   const void* b_o1=d_in[23];
  const void* W_o2=d_in[24];   const void* b_o2=d_in[25];

  float* ws = (float*)d_ws;
  float* ws_x     = ws;                       // B*E
  float* ws_h     = ws_x   + B*E;             // B*H
  float* ws_c     = ws_h   + B*H;             // B*H
  float* ws_dec   = ws_c   + B*H;             // B*H2
  float* ws_sc    = ws_dec + B*H2;            // B*T
  float* ws_attn  = ws_sc  + B*T;             // B*T
  float* ws_ct    = ws_attn+ B*T;             // B*H2
  float* ws_o1    = ws_ct  + B*H2;            // B*H
  float* ws_pg    = ws_o1  + B*H;             // B
  float* ws_log   = ws_pg  + B;               // B*V
  float* ws_flag  = ws_log + (size_t)B*V;     // 4

  k_detect  <<<dim3(1), dim3(64), 0, stream>>>(mask, ws_flag);
  k_zero    <<<dim3((B*H2+255)/256), dim3(256), 0, stream>>>(ws_ct, B*H2);

  k_embed_x<IOb><<<dim3(B), dim3(128), 0, stream>>>(ws_flag, y_t_1, c_t_1, emb, W_xc, b_xc, ws_x);
  k_embed_x<IOf><<<dim3(B), dim3(128), 0, stream>>>(ws_flag, y_t_1, c_t_1, emb, W_xc, b_xc, ws_x);

  k_lstm<IOb><<<dim3(B), dim3(256), 0, stream>>>(ws_flag, ws_x, h0, c0, W_ih, W_hh, b_ih, b_hh,
                                                 ws_h, ws_c, d_out);
  k_lstm<IOf><<<dim3(B), dim3(256), 0, stream>>>(ws_flag, ws_x, h0, c0, W_ih, W_hh, b_ih, b_hh,
                                                 ws_h, ws_c, d_out);

  k_decfea<IOb><<<dim3(B), dim3(256), 0, stream>>>(ws_flag, ws_h, ws_c, W_dp, b_dp, ws_dec);
  k_decfea<IOf><<<dim3(B), dim3(256), 0, stream>>>(ws_flag, ws_h, ws_c, W_dp, b_dp, ws_dec);

  k_scores<IOb><<<dim3(B*(T/16)), dim3(256), 0, stream>>>(ws_flag, enc_feat, ws_dec, W_c, v_w, coverage, ws_sc);
  k_scores<IOf><<<dim3(B*(T/16)), dim3(256), 0, stream>>>(ws_flag, enc_feat, ws_dec, W_c, v_w, coverage, ws_sc);

  k_attn<IOb><<<dim3(B), dim3(512), 0, stream>>>(ws_flag, ws_sc, mask, coverage, ws_attn, d_out);
  k_attn<IOf><<<dim3(B), dim3(512), 0, stream>>>(ws_flag, ws_sc, mask, coverage, ws_attn, d_out);

  k_ctx<IOb><<<dim3(B*8), dim3(256), 0, stream>>>(ws_flag, enc_out, ws_attn, ws_ct);
  k_ctx<IOf><<<dim3(B*8), dim3(256), 0, stream>>>(ws_flag, enc_out, ws_attn, ws_ct);

  k_pgen<IOb><<<dim3(B), dim3(256), 0, stream>>>(ws_flag, ws_ct, ws_h, ws_c, ws_x, W_pg, b_pg, ws_pg, d_out);
  k_pgen<IOf><<<dim3(B), dim3(256), 0, stream>>>(ws_flag, ws_ct, ws_h, ws_c, ws_x, W_pg, b_pg, ws_pg, d_out);

  k_o1<IOb><<<dim3(B), dim3(256), 0, stream>>>(ws_flag, ws_h, ws_ct, W_o1, b_o1, ws_o1);
  k_o1<IOf><<<dim3(B), dim3(256), 0, stream>>>(ws_flag, ws_h, ws_ct, W_o1, b_o1, ws_o1);

  k_logits<IOb><<<dim3((V+63)/64), dim3(256), 0, stream>>>(ws_flag, ws_o1, W_o2, b_o2, ws_log);
  k_logits<IOf><<<dim3((V+63)/64), dim3(256), 0, stream>>>(ws_flag, ws_o1, W_o2, b_o2, ws_log);

  k_vsoft   <<<dim3(B), dim3(256), 0, stream>>>(ws_log, ws_pg, ws_log);
  k_scatter <<<dim3((B*T+255)/256), dim3(256), 0, stream>>>(ext, ws_attn, ws_pg, ws_log);

  k_tostore<IOb><<<dim3((B*V/8+255)/256), dim3(256), 0, stream>>>(ws_flag, ws_log, d_out, B*V/8);
  k_tostore<IOf><<<dim3((B*V/8+255)/256), dim3(256), 0, stream>>>(ws_flag, ws_log, d_out, B*V/8);
}